// Round 10
// baseline (740.767 us; speedup 1.0000x reference)
//
#include <hip/hip_runtime.h>
#include <hip/hip_fp16.h>
#include <math.h>

// GCN: out = D^-1/2 (A+I) D^-1/2 (x W^T) + b per layer, ReLU between layers.
// R1: multiblock scan. R2: fp16 G + gather ILP. R3: MFMA split-fp16 GEMM.
// R4-R6: counting-sort graph build. R7 FAILED: blockIdx%4 "XCD" chunking.
// R8: ILP-8 gather (303us). R9 FAILED: agg+gemm fusion (TLP collapse).
// R10: XCD-affine FEATURE-CHUNKED aggregation done right: G stored chunk-major
// (Gc[4][N][32h], 3.2MB/chunk fits a 4MB per-XCD L2); blocks read their real
// XCD via s_getreg(HW_REG_XCC_ID) and drain that chunk's tile queue first
// (atomic work queues + stealing => output independent of block->XCD mapping).
// Per-XCD compulsory fetch drops 12.8MB -> 3.2MB (chip: 93MB -> ~26MB/layer).

typedef _Float16 f16x8 __attribute__((ext_vector_type(8)));
typedef float f32x4 __attribute__((ext_vector_type(4)));

#define NBIN 128
#define NB 512       // histogram/scatter blocks
#define WCAP 12288   // k_build LDS col-window entries (48 KB)
// s_getreg imm: id=20 (HW_REG_XCC_ID, gfx940+), offset=0, size=32 -> 20|(31<<11)
#define GETREG_XCC_ID 63508

// ---------------- graph build ----------------

__device__ __forceinline__ int edge_at(const void* ei, int is64, long long idx) {
  if (is64) return (int)((const long long*)ei)[idx];
  return ((const int*)ei)[idx];
}

__device__ __forceinline__ int detect_is64(const int* ei32, int E, int* ldsflag, int tid) {
  if (tid == 0) *ldsflag = 0;
  __syncthreads();
  int lim = (E < 256) ? E : 256;
  if (tid < lim) {
    if (ei32[2 * tid + 1] != 0) atomicOr(ldsflag, 1);
  }
  __syncthreads();
  return (*ldsflag == 0) ? 1 : 0;
}

__global__ __launch_bounds__(512) void k_cnt2(const void* __restrict__ ei, int* __restrict__ bcnt,
                                              int E, int n, int W) {
  __shared__ int cnt[NBIN];
  __shared__ int f64;
  int t = threadIdx.x;
  int is64 = detect_is64((const int*)ei, E, &f64, t);
  if (t < NBIN) cnt[t] = 0;
  __syncthreads();
  int chunk = (E + NB - 1) / NB;
  int base = blockIdx.x * chunk;
  int end = base + chunk;
  if (end > E) end = E;
  for (int i = base + t; i < end; i += 512) {
    int s = edge_at(ei, is64, i);
    int v = edge_at(ei, is64, (long long)E + i);
    if ((unsigned)v < (unsigned)n && (unsigned)s < (unsigned)n) atomicAdd(&cnt[v / W], 1);
  }
  __syncthreads();
  if (t < NBIN) bcnt[blockIdx.x * NBIN + t] = cnt[t];
}

__global__ __launch_bounds__(256) void k_scanb(int* __restrict__ bcnt, int* __restrict__ bintot) {
  __shared__ int buf[NB];
  int bin = blockIdx.x;
  int t = threadIdx.x;
  int a0 = bcnt[(size_t)t * NBIN + bin];
  int a1 = bcnt[(size_t)(t + 256) * NBIN + bin];
  buf[t] = a0;
  buf[t + 256] = a1;
  __syncthreads();
  for (int off = 1; off < NB; off <<= 1) {
    int x0 = (t >= off) ? buf[t - off] : 0;
    int x1 = (t + 256 >= off) ? buf[t + 256 - off] : 0;
    __syncthreads();
    buf[t] += x0;
    buf[t + 256] += x1;
    __syncthreads();
  }
  bcnt[(size_t)t * NBIN + bin] = buf[t] - a0;
  bcnt[(size_t)(t + 256) * NBIN + bin] = buf[t + 256] - a1;
  if (t == 255) bintot[bin] = buf[NB - 1];
}

__global__ __launch_bounds__(512) void k_scat(const void* __restrict__ ei, const int* __restrict__ bintot,
                                              const int* __restrict__ bcnt, uint2* __restrict__ ebin,
                                              int E, int n, int W) {
  __shared__ int f64;
  __shared__ int sb[NBIN];
  __shared__ int cur[NBIN];
  int t = threadIdx.x;
  int is64 = detect_is64((const int*)ei, E, &f64, t);
  if (t < NBIN) sb[t] = bintot[t];
  __syncthreads();
  for (int off = 1; off < NBIN; off <<= 1) {
    int x = 0;
    if (t < NBIN && t >= off) x = sb[t - off];
    __syncthreads();
    if (t < NBIN) sb[t] += x;
    __syncthreads();
  }
  if (t < NBIN) cur[t] = sb[t] - bintot[t] + bcnt[blockIdx.x * NBIN + t];
  __syncthreads();
  int chunk = (E + NB - 1) / NB;
  int base = blockIdx.x * chunk;
  int end = base + chunk;
  if (end > E) end = E;
  for (int i = base + t; i < end; i += 512) {
    int s = edge_at(ei, is64, i);
    int v = edge_at(ei, is64, (long long)E + i);
    if ((unsigned)v < (unsigned)n && (unsigned)s < (unsigned)n) {
      int pos = atomicAdd(&cur[v / W], 1);
      ebin[pos] = make_uint2((unsigned)s, (unsigned)v);
    }
  }
}

__global__ __launch_bounds__(256) void k_build(const uint2* __restrict__ ebin, const int* __restrict__ bintot,
                                               int* __restrict__ row_ptr, float* __restrict__ dinv,
                                               int* __restrict__ col, int n, int W) {
  __shared__ int hist[512];
  __shared__ int scanBuf[512];
  __shared__ int sb[NBIN];
  __shared__ unsigned int win[WCAP];
  int t = threadIdx.x;
  int b = blockIdx.x;
  if (t < NBIN) sb[t] = bintot[t];
  __syncthreads();
  for (int off = 1; off < NBIN; off <<= 1) {
    int x = 0;
    if (t < NBIN && t >= off) x = sb[t - off];
    __syncthreads();
    if (t < NBIN) sb[t] += x;
    __syncthreads();
  }
  int ebase = sb[b] - bintot[b];
  int ecnt = bintot[b];
  int etotal = sb[NBIN - 1];

  int v0 = b * W;
  int v1 = v0 + W;
  if (v1 > n) v1 = n;
  int nloc = v1 - v0;
  if (nloc <= 0) {
    if (b == NBIN - 1 && t == 0) row_ptr[n] = etotal;
    return;
  }

  for (int i = t; i < 512; i += 256) { hist[i] = 0; scanBuf[i] = 0; }
  __syncthreads();
  for (int j = t; j < ecnt; j += 256) {
    uint2 e = ebin[ebase + j];
    atomicAdd(&hist[(int)e.y - v0], 1);
  }
  __syncthreads();
  for (int i = t; i < nloc; i += 256) {
    scanBuf[i] = hist[i];
    dinv[v0 + i] = 1.0f / sqrtf((float)(hist[i] + 1));  // +1 self-loop
  }
  __syncthreads();
  int i1 = t, i2 = t + 256;
  for (int off = 1; off < 512; off <<= 1) {
    int a = (i1 >= off) ? scanBuf[i1 - off] : 0;
    int c = (i2 >= off) ? scanBuf[i2 - off] : 0;
    __syncthreads();
    scanBuf[i1] += a;
    scanBuf[i2] += c;
    __syncthreads();
  }
  for (int i = t; i < nloc; i += 256) row_ptr[v0 + i] = ebase + scanBuf[i] - hist[i];
  if (b == NBIN - 1 && t == 0) row_ptr[n] = etotal;
  __syncthreads();
  for (int i = t; i < nloc; i += 256) hist[i] = scanBuf[i] - hist[i];  // cursor
  __syncthreads();
  if (ecnt <= WCAP) {
    for (int j = t; j < ecnt; j += 256) {
      uint2 e = ebin[ebase + j];
      int pos = atomicAdd(&hist[(int)e.y - v0], 1);
      win[pos] = e.x;
    }
    __syncthreads();
    for (int j = t; j < ecnt; j += 256) col[ebase + j] = (int)win[j];  // coalesced
  } else {
    for (int j = t; j < ecnt; j += 256) {
      uint2 e = ebin[ebase + j];
      int pos = atomicAdd(&hist[(int)e.y - v0], 1);
      col[ebase + pos] = (int)e.x;
    }
  }
}

// ---------------- fp32 -> (h, r) fp16 splits ----------------

__global__ __launch_bounds__(256) void k_split_x(const float* __restrict__ X, unsigned int* __restrict__ Xh,
                                                 unsigned int* __restrict__ Xr, int n2) {
  int i = blockIdx.x * 256 + threadIdx.x;
  if (i >= n2) return;
  float2 v = ((const float2*)X)[i];
  __half hx = __float2half(v.x), hy = __float2half(v.y);
  float rx = v.x - __half2float(hx), ry = v.y - __half2float(hy);
  __half rxh = __float2half(rx), ryh = __float2half(ry);
  Xh[i] = ((unsigned int)*(unsigned short*)&hy << 16) | *(unsigned short*)&hx;
  Xr[i] = ((unsigned int)*(unsigned short*)&ryh << 16) | *(unsigned short*)&rxh;
}

__global__ __launch_bounds__(256) void k_split_wall(const float* __restrict__ W0, const float* __restrict__ W1,
                                                    const float* __restrict__ W2, const float* __restrict__ W3,
                                                    const float* __restrict__ W4, unsigned short* __restrict__ Wh,
                                                    unsigned short* __restrict__ Wr, int total) {
  int i = blockIdx.x * 256 + threadIdx.x;
  if (i >= total) return;
  const float* src;
  int off;
  if (i < 65536) {
    int l = i >> 14;
    off = i & 16383;
    src = (l == 0) ? W0 : (l == 1) ? W1 : (l == 2) ? W2 : W3;
  } else {
    off = i - 65536;
    src = W4;
  }
  float v = src[off];
  __half h = __float2half(v);
  float r = v - __half2float(h);
  __half rh = __float2half(r);
  Wh[i] = *(unsigned short*)&h;
  Wr[i] = *(unsigned short*)&rh;
}

// ---------------- MFMA GEMM: out = fp16( dinv * ((Xh+Xr) @ (Wh+Wr)^T) ) ----------------
// CHUNKED=true: output chunk-major Gc[chunk=j>>5][row][j&31] (64B chunks,
// 3.2MB contiguous per chunk). CHUNKED=false: row-major (layer-4 / D=64 path).

template <int DO, bool CHUNKED>
__global__ __launch_bounds__(256) void gemm_mfma(const unsigned short* __restrict__ Xh,
                                                 const unsigned short* __restrict__ Xr,
                                                 const unsigned short* __restrict__ Wh,
                                                 const unsigned short* __restrict__ Wr,
                                                 const float* __restrict__ dinv, __half* __restrict__ G, int n) {
  constexpr int NCG = DO / 16;
  __shared__ unsigned short sWh[DO * 128];
  __shared__ unsigned short sWr[DO * 128];
  const int tid = threadIdx.x;

#pragma unroll
  for (int it = 0; it < DO / 16; ++it) {
    int t = it * 256 + tid;
    int row = t >> 4, ch = t & 15;
    int sch = ch ^ (row & 7);
    const uint4* gh = (const uint4*)&Wh[(size_t)t * 8];
    const uint4* gr = (const uint4*)&Wr[(size_t)t * 8];
    *(uint4*)&sWh[row * 128 + sch * 8] = *gh;
    *(uint4*)&sWr[row * 128 + sch * 8] = *gr;
  }

  const int wv = tid >> 6;
  const int l = tid & 63;
  const int m = l & 15;
  const int ks = l >> 4;
  const int gr0 = blockIdx.x * 64 + wv * 16;
  const int arow = gr0 + m;

  f16x8 ah[4], ar[4];
  const f16x8 z8 = {0, 0, 0, 0, 0, 0, 0, 0};
#pragma unroll
  for (int kb = 0; kb < 4; ++kb) {
    int koff = kb * 32 + ks * 8;
    if (arow < n) {
      ah[kb] = *(const f16x8*)&Xh[(size_t)arow * 128 + koff];
      ar[kb] = *(const f16x8*)&Xr[(size_t)arow * 128 + koff];
    } else {
      ah[kb] = z8;
      ar[kb] = z8;
    }
  }

  f32x4 acc[NCG];
#pragma unroll
  for (int c = 0; c < NCG; ++c) acc[c] = {0.f, 0.f, 0.f, 0.f};

  __syncthreads();

#pragma unroll
  for (int kb = 0; kb < 4; ++kb) {
    int ch = (kb * 4 + ks) ^ (m & 7);
#pragma unroll
    for (int c = 0; c < NCG; ++c) {
      int brow = c * 16 + m;
      f16x8 bh = *(const f16x8*)&sWh[brow * 128 + ch * 8];
      f16x8 br = *(const f16x8*)&sWr[brow * 128 + ch * 8];
      acc[c] = __builtin_amdgcn_mfma_f32_16x16x32_f16(ah[kb], bh, acc[c], 0, 0, 0);
      acc[c] = __builtin_amdgcn_mfma_f32_16x16x32_f16(ah[kb], br, acc[c], 0, 0, 0);
      acc[c] = __builtin_amdgcn_mfma_f32_16x16x32_f16(ar[kb], bh, acc[c], 0, 0, 0);
    }
  }

  int r0 = gr0 + ks * 4;
  float dv[4];
#pragma unroll
  for (int i = 0; i < 4; ++i) dv[i] = (r0 + i < n) ? dinv[r0 + i] : 0.f;
#pragma unroll
  for (int c = 0; c < NCG; ++c) {
#pragma unroll
    for (int i = 0; i < 4; ++i) {
      int row = r0 + i;
      if (row < n) {
        __half val = __float2half(dv[i] * acc[c][i]);
        if (CHUNKED) {
          int j = c * 16 + m;
          G[(size_t)(j >> 5) * ((size_t)n * 32) + (size_t)row * 32 + (j & 31)] = val;
        } else {
          G[(size_t)row * DO + c * 16 + m] = val;
        }
      }
    }
  }
}

// ---------------- XCD-affine chunked aggregation (128-wide layers) ----------------

__device__ __forceinline__ float2 h2f(unsigned int u) {
  __half2 h = *(__half2*)&u;
  return __half22float2(h);
}

// Gc: chunk-major [4][n][16 uints]. Tile = 64 nodes. Per-chunk atomic queues;
// block prefers chunk (XCC_ID & 3), then steals. 16 lanes per node (one 64B
// line per edge gather), 4 nodes per wave, ILP-4 chains.
__global__ __launch_bounds__(256) void k_agg_chunk(const unsigned int* __restrict__ Gc,
                                                   const float* __restrict__ dinv,
                                                   const float* __restrict__ bias,
                                                   const int* __restrict__ rp, const int* __restrict__ col,
                                                   unsigned int* __restrict__ Yh, unsigned int* __restrict__ Yr,
                                                   int* __restrict__ cur, int n, int ntiles) {
  __shared__ int stile;
  const int tid = threadIdx.x;
  const int xcc = __builtin_amdgcn_s_getreg(GETREG_XCC_ID) & 15;
  const int mychunk = xcc & 3;
  const int grpid = tid >> 4;          // 0..15 node-groups per block
  const int r = tid & 15;              // lane within group = uint column
  const int grpbase = (tid & 63) & 48; // group's base lane within its wave

  for (int pass = 0; pass < 4; ++pass) {
    int chunk = (mychunk + pass) & 3;
    const unsigned int* gcb = Gc + (size_t)chunk * ((size_t)n * 16);
    const float2* bias2 = (const float2*)bias + chunk * 16;
    while (true) {
      if (tid == 0) stile = atomicAdd(&cur[chunk], 1);
      __syncthreads();
      int tile = stile;
      __syncthreads();
      if (tile >= ntiles) break;
#pragma unroll
      for (int it = 0; it < 4; ++it) {
        int v = tile * 64 + it * 16 + grpid;
        if (v >= n) continue;
        int s = rp[v], e = rp[v + 1];
        float2 a0 = h2f(gcb[(size_t)v * 16 + r]);  // self-loop
        float2 a1 = make_float2(0.f, 0.f), a2 = make_float2(0.f, 0.f), a3 = make_float2(0.f, 0.f);
        int t = s;
        while (t < e) {
          int rem = e - t;
          if (rem > 16) rem = 16;
          int ci = col[t + (r < rem ? r : rem - 1)];
          int j = 0;
          for (; j + 4 <= rem; j += 4) {
            int u0 = __shfl(ci, grpbase + j, 64);
            int u1 = __shfl(ci, grpbase + j + 1, 64);
            int u2 = __shfl(ci, grpbase + j + 2, 64);
            int u3 = __shfl(ci, grpbase + j + 3, 64);
            unsigned int g0 = gcb[(size_t)u0 * 16 + r];
            unsigned int g1 = gcb[(size_t)u1 * 16 + r];
            unsigned int g2 = gcb[(size_t)u2 * 16 + r];
            unsigned int g3 = gcb[(size_t)u3 * 16 + r];
            float2 f0 = h2f(g0), f1 = h2f(g1), f2 = h2f(g2), f3 = h2f(g3);
            a0.x += f0.x; a0.y += f0.y;
            a1.x += f1.x; a1.y += f1.y;
            a2.x += f2.x; a2.y += f2.y;
            a3.x += f3.x; a3.y += f3.y;
          }
          for (; j < rem; ++j) {
            int u = __shfl(ci, grpbase + j, 64);
            float2 f = h2f(gcb[(size_t)u * 16 + r]);
            a0.x += f.x; a0.y += f.y;
          }
          t += rem;
        }
        float sx = (a0.x + a1.x) + (a2.x + a3.x);
        float sy = (a0.y + a1.y) + (a2.y + a3.y);
        float dv = dinv[v];
        float2 bb = bias2[r];
        float ox = fmaxf(fmaf(dv, sx, bb.x), 0.f);  // ReLU (layers 0..3)
        float oy = fmaxf(fmaf(dv, sy, bb.y), 0.f);
        __half hx = __float2half(ox), hy = __float2half(oy);
        float rx = ox - __half2float(hx), ry = oy - __half2float(hy);
        __half rxh = __float2half(rx), ryh = __float2half(ry);
        size_t o = (size_t)v * 64 + chunk * 16 + r;
        Yh[o] = ((unsigned int)*(unsigned short*)&hy << 16) | *(unsigned short*)&hx;
        Yr[o] = ((unsigned int)*(unsigned short*)&ryh << 16) | *(unsigned short*)&rxh;
      }
    }
  }
}

// ---------------- final aggregation (layer 4, D=64 row-major -> d_out) ----------------

__global__ __launch_bounds__(256) void aggregate64(const unsigned short* __restrict__ G, const float* __restrict__ dinv,
                                                   const float* __restrict__ bias, const int* __restrict__ rp,
                                                   const int* __restrict__ col, float* __restrict__ Y, int n) {
  int v = (int)((blockIdx.x * 256 + threadIdx.x) >> 6);
  int lane = threadIdx.x & 63;
  if (v >= n) return;
  int s = rp[v], e = rp[v + 1];
  float a0 = __half2float(*(const __half*)&G[(size_t)v * 64 + lane]);
  float a1 = 0.f, a2 = 0.f, a3 = 0.f;
  float a4 = 0.f, a5 = 0.f, a6 = 0.f, a7 = 0.f;
  int t = s;
  while (t < e) {
    int batch = e - t;
    if (batch > 64) batch = 64;
    int ci = col[t + (lane < batch ? lane : batch - 1)];
    int j = 0;
    for (; j + 8 <= batch; j += 8) {
      int u0 = __shfl(ci, j, 64), u1 = __shfl(ci, j + 1, 64);
      int u2 = __shfl(ci, j + 2, 64), u3 = __shfl(ci, j + 3, 64);
      int u4 = __shfl(ci, j + 4, 64), u5 = __shfl(ci, j + 5, 64);
      int u6 = __shfl(ci, j + 6, 64), u7 = __shfl(ci, j + 7, 64);
      unsigned short g0 = G[(size_t)u0 * 64 + lane];
      unsigned short g1 = G[(size_t)u1 * 64 + lane];
      unsigned short g2 = G[(size_t)u2 * 64 + lane];
      unsigned short g3 = G[(size_t)u3 * 64 + lane];
      unsigned short g4 = G[(size_t)u4 * 64 + lane];
      unsigned short g5 = G[(size_t)u5 * 64 + lane];
      unsigned short g6 = G[(size_t)u6 * 64 + lane];
      unsigned short g7 = G[(size_t)u7 * 64 + lane];
      a0 += __half2float(*(const __half*)&g0);
      a1 += __half2float(*(const __half*)&g1);
      a2 += __half2float(*(const __half*)&g2);
      a3 += __half2float(*(const __half*)&g3);
      a4 += __half2float(*(const __half*)&g4);
      a5 += __half2float(*(const __half*)&g5);
      a6 += __half2float(*(const __half*)&g6);
      a7 += __half2float(*(const __half*)&g7);
    }
    for (; j < batch; ++j) {
      int u = __shfl(ci, j, 64);
      unsigned short g = G[(size_t)u * 64 + lane];
      a0 += __half2float(*(const __half*)&g);
    }
    t += batch;
  }
  float sum = ((a0 + a1) + (a2 + a3)) + ((a4 + a5) + (a6 + a7));
  Y[(size_t)v * 64 + lane] = fmaf(dinv[v], sum, bias[lane]);
}

// ---------------- launch ----------------

extern "C" void kernel_launch(void* const* d_in, const int* in_sizes, int n_in,
                              void* d_out, int out_size, void* d_ws, size_t ws_size,
                              hipStream_t stream) {
  const float* x = (const float*)d_in[0];
  const void* ei = d_in[1];
  const int N = in_sizes[0] / 128;
  const int E = in_sizes[1] / 2;
  const float* W[5] = {(const float*)d_in[2], (const float*)d_in[4], (const float*)d_in[6],
                       (const float*)d_in[8], (const float*)d_in[10]};
  const float* B[5] = {(const float*)d_in[3], (const float*)d_in[5], (const float*)d_in[7],
                       (const float*)d_in[9], (const float*)d_in[11]};
  const int Wbin = (N + NBIN - 1) / NBIN;

  char* p = (char*)d_ws;
  unsigned short* xyh = (unsigned short*)p;  p += (size_t)N * 128 * 2;   // activations h
  unsigned short* xyr = (unsigned short*)p;  p += (size_t)N * 128 * 2;   // activations r
  __half* g = (__half*)p;                    p += (size_t)N * 128 * 2;   // Gc (chunk-major) / row-major for layer 4
  uint2* ebin = (uint2*)g;                   // ALIAS: ebin dead before gemm0 writes g
  unsigned short* wh = (unsigned short*)p;   p += (size_t)5 * 16384 * 2;
  unsigned short* wr = (unsigned short*)p;   p += (size_t)5 * 16384 * 2;
  float* dinv = (float*)p;                   p += (size_t)N * 4;
  int* col = (int*)p;                        p += (size_t)E * 4;
  int* row_ptr = (int*)p;                    p += (size_t)(N + 1) * 4;
  int* bcnt = (int*)p;                       p += (size_t)NB * NBIN * 4;
  int* bintot = (int*)p;                     p += NBIN * 4;
  int* cur = (int*)p;                        p += 16 * 4;  // 4 layers x 4 chunk queues

  hipMemsetAsync(cur, 0, 16 * sizeof(int), stream);

  k_cnt2<<<NB, 512, 0, stream>>>(ei, bcnt, E, N, Wbin);
  k_scanb<<<NBIN, 256, 0, stream>>>(bcnt, bintot);
  k_scat<<<NB, 512, 0, stream>>>(ei, bintot, bcnt, ebin, E, N, Wbin);
  k_build<<<NBIN, 256, 0, stream>>>(ebin, bintot, row_ptr, dinv, col, N, Wbin);

  k_split_x<<<(N * 64 + 255) / 256, 256, 0, stream>>>(x, (unsigned int*)xyh, (unsigned int*)xyr, N * 64);
  k_split_wall<<<(73728 + 255) / 256, 256, 0, stream>>>(W[0], W[1], W[2], W[3], W[4], wh, wr, 73728);

  const int gb64 = (N + 63) / 64;
  const int ab = (N * 64 + 255) / 256;
  const int ntiles = (N + 63) / 64;

  for (int l = 0; l < 4; ++l) {
    gemm_mfma<128, true><<<gb64, 256, 0, stream>>>(xyh, xyr, wh + l * 16384, wr + l * 16384, dinv, g, N);
    k_agg_chunk<<<2048, 256, 0, stream>>>((const unsigned int*)g, dinv, B[l], row_ptr, col,
                                          (unsigned int*)xyh, (unsigned int*)xyr, cur + l * 4, N, ntiles);
  }
  gemm_mfma<64, false><<<gb64, 256, 0, stream>>>(xyh, xyr, wh + 4 * 16384, wr + 4 * 16384, dinv, g, N);
  aggregate64<<<ab, 256, 0, stream>>>((const unsigned short*)g, dinv, B[4], row_ptr, col, (float*)d_out, N);
}

// Round 11
// 313.690 us; speedup vs baseline: 2.3615x; 2.3615x over previous
//
#include <hip/hip_runtime.h>
#include <hip/hip_fp16.h>
#include <math.h>

// GCN: out = D^-1/2 (A+I) D^-1/2 (x W^T) + b per layer, ReLU between layers.
// R1: multiblock scan. R2: fp16 G + gather ILP. R3: MFMA split-fp16 GEMM.
// R4-R6: counting-sort graph build. R7 FAILED: blockIdx%4 chunking.
// R8: ILP-8 gather (303us best). R9 FAILED: fusion (TLP collapse).
// R10 FAILED: XCC_ID chunked agg — locality verified (FETCH 93->38MB) but
// 16 vs 32 sectors/wave in flight + queue serialization => 3.75x slower.
// Lesson: aggregate is request-throughput bound (~5.4TB/s logical via L3);
// maximize MLP. R11: R8 baseline + 16-wide gather issue (one round covers
// deg~17) + k_split_x folded into gemm0 (fp32 read, in-register h/r split).

typedef _Float16 f16x8 __attribute__((ext_vector_type(8)));
typedef float f32x4 __attribute__((ext_vector_type(4)));

#define NBIN 128
#define NB 512       // histogram/scatter blocks
#define WCAP 12288   // k_build LDS col-window entries (48 KB)

// ---------------- graph build ----------------

__device__ __forceinline__ int edge_at(const void* ei, int is64, long long idx) {
  if (is64) return (int)((const long long*)ei)[idx];
  return ((const int*)ei)[idx];
}

__device__ __forceinline__ int detect_is64(const int* ei32, int E, int* ldsflag, int tid) {
  if (tid == 0) *ldsflag = 0;
  __syncthreads();
  int lim = (E < 256) ? E : 256;
  if (tid < lim) {
    if (ei32[2 * tid + 1] != 0) atomicOr(ldsflag, 1);
  }
  __syncthreads();
  return (*ldsflag == 0) ? 1 : 0;
}

__global__ __launch_bounds__(512) void k_cnt2(const void* __restrict__ ei, int* __restrict__ bcnt,
                                              int E, int n, int W) {
  __shared__ int cnt[NBIN];
  __shared__ int f64;
  int t = threadIdx.x;
  int is64 = detect_is64((const int*)ei, E, &f64, t);
  if (t < NBIN) cnt[t] = 0;
  __syncthreads();
  int chunk = (E + NB - 1) / NB;
  int base = blockIdx.x * chunk;
  int end = base + chunk;
  if (end > E) end = E;
  for (int i = base + t; i < end; i += 512) {
    int s = edge_at(ei, is64, i);
    int v = edge_at(ei, is64, (long long)E + i);
    if ((unsigned)v < (unsigned)n && (unsigned)s < (unsigned)n) atomicAdd(&cnt[v / W], 1);
  }
  __syncthreads();
  if (t < NBIN) bcnt[blockIdx.x * NBIN + t] = cnt[t];
}

__global__ __launch_bounds__(256) void k_scanb(int* __restrict__ bcnt, int* __restrict__ bintot) {
  __shared__ int buf[NB];
  int bin = blockIdx.x;
  int t = threadIdx.x;
  int a0 = bcnt[(size_t)t * NBIN + bin];
  int a1 = bcnt[(size_t)(t + 256) * NBIN + bin];
  buf[t] = a0;
  buf[t + 256] = a1;
  __syncthreads();
  for (int off = 1; off < NB; off <<= 1) {
    int x0 = (t >= off) ? buf[t - off] : 0;
    int x1 = (t + 256 >= off) ? buf[t + 256 - off] : 0;
    __syncthreads();
    buf[t] += x0;
    buf[t + 256] += x1;
    __syncthreads();
  }
  bcnt[(size_t)t * NBIN + bin] = buf[t] - a0;
  bcnt[(size_t)(t + 256) * NBIN + bin] = buf[t + 256] - a1;
  if (t == 255) bintot[bin] = buf[NB - 1];
}

__global__ __launch_bounds__(512) void k_scat(const void* __restrict__ ei, const int* __restrict__ bintot,
                                              const int* __restrict__ bcnt, uint2* __restrict__ ebin,
                                              int E, int n, int W) {
  __shared__ int f64;
  __shared__ int sb[NBIN];
  __shared__ int cur[NBIN];
  int t = threadIdx.x;
  int is64 = detect_is64((const int*)ei, E, &f64, t);
  if (t < NBIN) sb[t] = bintot[t];
  __syncthreads();
  for (int off = 1; off < NBIN; off <<= 1) {
    int x = 0;
    if (t < NBIN && t >= off) x = sb[t - off];
    __syncthreads();
    if (t < NBIN) sb[t] += x;
    __syncthreads();
  }
  if (t < NBIN) cur[t] = sb[t] - bintot[t] + bcnt[blockIdx.x * NBIN + t];
  __syncthreads();
  int chunk = (E + NB - 1) / NB;
  int base = blockIdx.x * chunk;
  int end = base + chunk;
  if (end > E) end = E;
  for (int i = base + t; i < end; i += 512) {
    int s = edge_at(ei, is64, i);
    int v = edge_at(ei, is64, (long long)E + i);
    if ((unsigned)v < (unsigned)n && (unsigned)s < (unsigned)n) {
      int pos = atomicAdd(&cur[v / W], 1);
      ebin[pos] = make_uint2((unsigned)s, (unsigned)v);
    }
  }
}

__global__ __launch_bounds__(256) void k_build(const uint2* __restrict__ ebin, const int* __restrict__ bintot,
                                               int* __restrict__ row_ptr, float* __restrict__ dinv,
                                               int* __restrict__ col, int n, int W) {
  __shared__ int hist[512];
  __shared__ int scanBuf[512];
  __shared__ int sb[NBIN];
  __shared__ unsigned int win[WCAP];
  int t = threadIdx.x;
  int b = blockIdx.x;
  if (t < NBIN) sb[t] = bintot[t];
  __syncthreads();
  for (int off = 1; off < NBIN; off <<= 1) {
    int x = 0;
    if (t < NBIN && t >= off) x = sb[t - off];
    __syncthreads();
    if (t < NBIN) sb[t] += x;
    __syncthreads();
  }
  int ebase = sb[b] - bintot[b];
  int ecnt = bintot[b];
  int etotal = sb[NBIN - 1];

  int v0 = b * W;
  int v1 = v0 + W;
  if (v1 > n) v1 = n;
  int nloc = v1 - v0;
  if (nloc <= 0) {
    if (b == NBIN - 1 && t == 0) row_ptr[n] = etotal;
    return;
  }

  for (int i = t; i < 512; i += 256) { hist[i] = 0; scanBuf[i] = 0; }
  __syncthreads();
  for (int j = t; j < ecnt; j += 256) {
    uint2 e = ebin[ebase + j];
    atomicAdd(&hist[(int)e.y - v0], 1);
  }
  __syncthreads();
  for (int i = t; i < nloc; i += 256) {
    scanBuf[i] = hist[i];
    dinv[v0 + i] = 1.0f / sqrtf((float)(hist[i] + 1));  // +1 self-loop
  }
  __syncthreads();
  int i1 = t, i2 = t + 256;
  for (int off = 1; off < 512; off <<= 1) {
    int a = (i1 >= off) ? scanBuf[i1 - off] : 0;
    int c = (i2 >= off) ? scanBuf[i2 - off] : 0;
    __syncthreads();
    scanBuf[i1] += a;
    scanBuf[i2] += c;
    __syncthreads();
  }
  for (int i = t; i < nloc; i += 256) row_ptr[v0 + i] = ebase + scanBuf[i] - hist[i];
  if (b == NBIN - 1 && t == 0) row_ptr[n] = etotal;
  __syncthreads();
  for (int i = t; i < nloc; i += 256) hist[i] = scanBuf[i] - hist[i];  // cursor
  __syncthreads();
  if (ecnt <= WCAP) {
    for (int j = t; j < ecnt; j += 256) {
      uint2 e = ebin[ebase + j];
      int pos = atomicAdd(&hist[(int)e.y - v0], 1);
      win[pos] = e.x;
    }
    __syncthreads();
    for (int j = t; j < ecnt; j += 256) col[ebase + j] = (int)win[j];  // coalesced
  } else {
    for (int j = t; j < ecnt; j += 256) {
      uint2 e = ebin[ebase + j];
      int pos = atomicAdd(&hist[(int)e.y - v0], 1);
      col[ebase + pos] = (int)e.x;
    }
  }
}

// ---------------- weight split ----------------

__global__ __launch_bounds__(256) void k_split_wall(const float* __restrict__ W0, const float* __restrict__ W1,
                                                    const float* __restrict__ W2, const float* __restrict__ W3,
                                                    const float* __restrict__ W4, unsigned short* __restrict__ Wh,
                                                    unsigned short* __restrict__ Wr, int total) {
  int i = blockIdx.x * 256 + threadIdx.x;
  if (i >= total) return;
  const float* src;
  int off;
  if (i < 65536) {
    int l = i >> 14;
    off = i & 16383;
    src = (l == 0) ? W0 : (l == 1) ? W1 : (l == 2) ? W2 : W3;
  } else {
    off = i - 65536;
    src = W4;
  }
  float v = src[off];
  __half h = __float2half(v);
  float r = v - __half2float(h);
  __half rh = __float2half(r);
  Wh[i] = *(unsigned short*)&h;
  Wr[i] = *(unsigned short*)&rh;
}

// ---------------- MFMA GEMMs ----------------
// Common body: A-frags ah/ar (split-fp16), W h+r staged in LDS with XOR chunk
// swizzle; acc = ah*Wh + ah*Wr + ar*Wh; epilogue dinv scale -> fp16 G.

template <int DO>
__device__ __forceinline__ void gemm_core(const f16x8 ah[4], const f16x8 ar[4],
                                          const unsigned short* __restrict__ Wh,
                                          const unsigned short* __restrict__ Wr,
                                          const float* __restrict__ dinv, __half* __restrict__ G,
                                          unsigned short* sWh, unsigned short* sWr,
                                          int tid, int n, int gr0) {
  constexpr int NCG = DO / 16;
  const int l = tid & 63;
  const int m = l & 15;
  const int ks = l >> 4;

  f32x4 acc[NCG];
#pragma unroll
  for (int c = 0; c < NCG; ++c) acc[c] = {0.f, 0.f, 0.f, 0.f};

  __syncthreads();

#pragma unroll
  for (int kb = 0; kb < 4; ++kb) {
    int ch = (kb * 4 + ks) ^ (m & 7);
#pragma unroll
    for (int c = 0; c < NCG; ++c) {
      int brow = c * 16 + m;
      f16x8 bh = *(const f16x8*)&sWh[brow * 128 + ch * 8];
      f16x8 br = *(const f16x8*)&sWr[brow * 128 + ch * 8];
      acc[c] = __builtin_amdgcn_mfma_f32_16x16x32_f16(ah[kb], bh, acc[c], 0, 0, 0);
      acc[c] = __builtin_amdgcn_mfma_f32_16x16x32_f16(ah[kb], br, acc[c], 0, 0, 0);
      acc[c] = __builtin_amdgcn_mfma_f32_16x16x32_f16(ar[kb], bh, acc[c], 0, 0, 0);
    }
  }

  int r0 = gr0 + ks * 4;
  float dv[4];
#pragma unroll
  for (int i = 0; i < 4; ++i) dv[i] = (r0 + i < n) ? dinv[r0 + i] : 0.f;
#pragma unroll
  for (int c = 0; c < NCG; ++c) {
#pragma unroll
    for (int i = 0; i < 4; ++i) {
      int row = r0 + i;
      if (row < n) G[(size_t)row * DO + c * 16 + m] = __float2half(dv[i] * acc[c][i]);
    }
  }
}

template <int DO>
__device__ __forceinline__ void stage_w(const unsigned short* __restrict__ Wh,
                                        const unsigned short* __restrict__ Wr,
                                        unsigned short* sWh, unsigned short* sWr, int tid) {
#pragma unroll
  for (int it = 0; it < DO / 16; ++it) {
    int t = it * 256 + tid;
    int row = t >> 4, ch = t & 15;
    int sch = ch ^ (row & 7);
    *(uint4*)&sWh[row * 128 + sch * 8] = *(const uint4*)&Wh[(size_t)t * 8];
    *(uint4*)&sWr[row * 128 + sch * 8] = *(const uint4*)&Wr[(size_t)t * 8];
  }
}

// layers 1..4: A from pre-split xyh/xyr
template <int DO>
__global__ __launch_bounds__(256) void gemm_mfma(const unsigned short* __restrict__ Xh,
                                                 const unsigned short* __restrict__ Xr,
                                                 const unsigned short* __restrict__ Wh,
                                                 const unsigned short* __restrict__ Wr,
                                                 const float* __restrict__ dinv, __half* __restrict__ G, int n) {
  __shared__ unsigned short sWh[DO * 128];
  __shared__ unsigned short sWr[DO * 128];
  const int tid = threadIdx.x;
  stage_w<DO>(Wh, Wr, sWh, sWr, tid);

  const int wv = tid >> 6;
  const int l = tid & 63;
  const int m = l & 15;
  const int ks = l >> 4;
  const int gr0 = blockIdx.x * 64 + wv * 16;
  const int arow = gr0 + m;

  f16x8 ah[4], ar[4];
  const f16x8 z8 = {0, 0, 0, 0, 0, 0, 0, 0};
#pragma unroll
  for (int kb = 0; kb < 4; ++kb) {
    int koff = kb * 32 + ks * 8;
    if (arow < n) {
      ah[kb] = *(const f16x8*)&Xh[(size_t)arow * 128 + koff];
      ar[kb] = *(const f16x8*)&Xr[(size_t)arow * 128 + koff];
    } else {
      ah[kb] = z8;
      ar[kb] = z8;
    }
  }
  gemm_core<DO>(ah, ar, Wh, Wr, dinv, G, sWh, sWr, tid, n, gr0);
}

// layer 0: A read as fp32 from x, split h/r in-register (same RNE ops as
// k_split_x -> bit-identical), deleting the 38MB split pass.
__global__ __launch_bounds__(256) void gemm_mfma_f32(const float* __restrict__ X,
                                                     const unsigned short* __restrict__ Wh,
                                                     const unsigned short* __restrict__ Wr,
                                                     const float* __restrict__ dinv, __half* __restrict__ G, int n) {
  __shared__ unsigned short sWh[128 * 128];
  __shared__ unsigned short sWr[128 * 128];
  const int tid = threadIdx.x;
  stage_w<128>(Wh, Wr, sWh, sWr, tid);

  const int wv = tid >> 6;
  const int l = tid & 63;
  const int m = l & 15;
  const int ks = l >> 4;
  const int gr0 = blockIdx.x * 64 + wv * 16;
  const int arow = gr0 + m;

  f16x8 ah[4], ar[4];
#pragma unroll
  for (int kb = 0; kb < 4; ++kb) {
    int koff = kb * 32 + ks * 8;
    if (arow < n) {
      float4 v0 = *(const float4*)&X[(size_t)arow * 128 + koff];
      float4 v1 = *(const float4*)&X[(size_t)arow * 128 + koff + 4];
      float vv[8] = {v0.x, v0.y, v0.z, v0.w, v1.x, v1.y, v1.z, v1.w};
#pragma unroll
      for (int j = 0; j < 8; ++j) {
        _Float16 h = (_Float16)vv[j];          // RNE, == __float2half
        float r = vv[j] - (float)h;
        ah[kb][j] = h;
        ar[kb][j] = (_Float16)r;
      }
    } else {
#pragma unroll
      for (int j = 0; j < 8; ++j) { ah[kb][j] = (_Float16)0.f; ar[kb][j] = (_Float16)0.f; }
    }
  }
  gemm_core<128>(ah, ar, Wh, Wr, dinv, G, sWh, sWr, tid, n, gr0);
}

// ---------------- aggregation (16-wide gather issue, 8 acc chains) ----------------

__device__ __forceinline__ float2 h2f(unsigned int u) {
  __half2 h = *(__half2*)&u;
  return __half22float2(h);
}

__global__ __launch_bounds__(256) void aggregate128(const unsigned int* __restrict__ G, const float* __restrict__ dinv,
                                                    const float* __restrict__ bias, const int* __restrict__ rp,
                                                    const int* __restrict__ col, unsigned int* __restrict__ Yh,
                                                    unsigned int* __restrict__ Yr, int n) {
  int v = (int)((blockIdx.x * 256 + threadIdx.x) >> 6);
  int lane = threadIdx.x & 63;
  if (v >= n) return;
  int s = rp[v], e = rp[v + 1];
  float2 a[8];
  a[0] = h2f(G[(size_t)v * 64 + lane]);  // self-loop
#pragma unroll
  for (int k = 1; k < 8; ++k) a[k] = make_float2(0.f, 0.f);
  int t = s;
  while (t < e) {
    int batch = e - t;
    if (batch > 64) batch = 64;
    int ci = col[t + (lane < batch ? lane : batch - 1)];
    int j = 0;
    for (; j + 16 <= batch; j += 16) {
      unsigned int g[16];
#pragma unroll
      for (int k = 0; k < 16; ++k) {
        int u = __shfl(ci, j + k, 64);
        g[k] = G[(size_t)u * 64 + lane];
      }
#pragma unroll
      for (int k = 0; k < 16; ++k) {
        float2 f = h2f(g[k]);
        a[k & 7].x += f.x;
        a[k & 7].y += f.y;
      }
    }
    for (; j + 8 <= batch; j += 8) {
      unsigned int g[8];
#pragma unroll
      for (int k = 0; k < 8; ++k) {
        int u = __shfl(ci, j + k, 64);
        g[k] = G[(size_t)u * 64 + lane];
      }
#pragma unroll
      for (int k = 0; k < 8; ++k) {
        float2 f = h2f(g[k]);
        a[k].x += f.x;
        a[k].y += f.y;
      }
    }
    for (; j < batch; ++j) {
      int u = __shfl(ci, j, 64);
      float2 f = h2f(G[(size_t)u * 64 + lane]);
      a[0].x += f.x;
      a[0].y += f.y;
    }
    t += batch;
  }
  float sx = ((a[0].x + a[1].x) + (a[2].x + a[3].x)) + ((a[4].x + a[5].x) + (a[6].x + a[7].x));
  float sy = ((a[0].y + a[1].y) + (a[2].y + a[3].y)) + ((a[4].y + a[5].y) + (a[6].y + a[7].y));
  float dv = dinv[v];
  float2 bb = ((const float2*)bias)[lane];
  float ox = fmaxf(fmaf(dv, sx, bb.x), 0.f);  // ReLU
  float oy = fmaxf(fmaf(dv, sy, bb.y), 0.f);
  __half hx = __float2half(ox), hy = __float2half(oy);
  float rx = ox - __half2float(hx), ry = oy - __half2float(hy);
  __half rxh = __float2half(rx), ryh = __float2half(ry);
  size_t o = (size_t)v * 64 + lane;
  Yh[o] = ((unsigned int)*(unsigned short*)&hy << 16) | *(unsigned short*)&hx;
  Yr[o] = ((unsigned int)*(unsigned short*)&ryh << 16) | *(unsigned short*)&rxh;
}

__global__ __launch_bounds__(256) void aggregate64(const unsigned short* __restrict__ G, const float* __restrict__ dinv,
                                                   const float* __restrict__ bias, const int* __restrict__ rp,
                                                   const int* __restrict__ col, float* __restrict__ Y, int n) {
  int v = (int)((blockIdx.x * 256 + threadIdx.x) >> 6);
  int lane = threadIdx.x & 63;
  if (v >= n) return;
  int s = rp[v], e = rp[v + 1];
  float a[8];
  a[0] = __half2float(*(const __half*)&G[(size_t)v * 64 + lane]);
#pragma unroll
  for (int k = 1; k < 8; ++k) a[k] = 0.f;
  int t = s;
  while (t < e) {
    int batch = e - t;
    if (batch > 64) batch = 64;
    int ci = col[t + (lane < batch ? lane : batch - 1)];
    int j = 0;
    for (; j + 16 <= batch; j += 16) {
      unsigned short g[16];
#pragma unroll
      for (int k = 0; k < 16; ++k) {
        int u = __shfl(ci, j + k, 64);
        g[k] = G[(size_t)u * 64 + lane];
      }
#pragma unroll
      for (int k = 0; k < 16; ++k) a[k & 7] += __half2float(*(const __half*)&g[k]);
    }
    for (; j + 8 <= batch; j += 8) {
      unsigned short g[8];
#pragma unroll
      for (int k = 0; k < 8; ++k) {
        int u = __shfl(ci, j + k, 64);
        g[k] = G[(size_t)u * 64 + lane];
      }
#pragma unroll
      for (int k = 0; k < 8; ++k) a[k] += __half2float(*(const __half*)&g[k]);
    }
    for (; j < batch; ++j) {
      int u = __shfl(ci, j, 64);
      unsigned short g = G[(size_t)u * 64 + lane];
      a[0] += __half2float(*(const __half*)&g);
    }
    t += batch;
  }
  float sum = ((a[0] + a[1]) + (a[2] + a[3])) + ((a[4] + a[5]) + (a[6] + a[7]));
  Y[(size_t)v * 64 + lane] = fmaf(dinv[v], sum, bias[lane]);
}

// ---------------- launch ----------------

extern "C" void kernel_launch(void* const* d_in, const int* in_sizes, int n_in,
                              void* d_out, int out_size, void* d_ws, size_t ws_size,
                              hipStream_t stream) {
  const float* x = (const float*)d_in[0];
  const void* ei = d_in[1];
  const int N = in_sizes[0] / 128;
  const int E = in_sizes[1] / 2;
  const float* W[5] = {(const float*)d_in[2], (const float*)d_in[4], (const float*)d_in[6],
                       (const float*)d_in[8], (const float*)d_in[10]};
  const float* B[5] = {(const float*)d_in[3], (const float*)d_in[5], (const float*)d_in[7],
                       (const float*)d_in[9], (const float*)d_in[11]};
  const int Wbin = (N + NBIN - 1) / NBIN;

  char* p = (char*)d_ws;
  unsigned short* xyh = (unsigned short*)p;  p += (size_t)N * 128 * 2;   // activations h
  unsigned short* xyr = (unsigned short*)p;  p += (size_t)N * 128 * 2;   // activations r
  __half* g = (__half*)p;                    p += (size_t)N * 128 * 2;   // post-GEMM dinv.*h
  uint2* ebin = (uint2*)g;                   // ALIAS: ebin dead before gemm0 writes g
  unsigned short* wh = (unsigned short*)p;   p += (size_t)5 * 16384 * 2;
  unsigned short* wr = (unsigned short*)p;   p += (size_t)5 * 16384 * 2;
  float* dinv = (float*)p;                   p += (size_t)N * 4;
  int* col = (int*)p;                        p += (size_t)E * 4;
  int* row_ptr = (int*)p;                    p += (size_t)(N + 1) * 4;
  int* bcnt = (int*)p;                       p += (size_t)NB * NBIN * 4;
  int* bintot = (int*)p;                     p += NBIN * 4;

  k_cnt2<<<NB, 512, 0, stream>>>(ei, bcnt, E, N, Wbin);
  k_scanb<<<NBIN, 256, 0, stream>>>(bcnt, bintot);
  k_scat<<<NB, 512, 0, stream>>>(ei, bintot, bcnt, ebin, E, N, Wbin);
  k_build<<<NBIN, 256, 0, stream>>>(ebin, bintot, row_ptr, dinv, col, N, Wbin);

  k_split_wall<<<(73728 + 255) / 256, 256, 0, stream>>>(W[0], W[1], W[2], W[3], W[4], wh, wr, 73728);

  const int gb64 = (N + 63) / 64;
  const int ab = (N * 64 + 255) / 256;

  // layer 0: fp32 x read directly (in-register split), -> g
  gemm_mfma_f32<<<gb64, 256, 0, stream>>>(x, wh, wr, dinv, g, N);
  aggregate128<<<ab, 256, 0, stream>>>((const unsigned int*)g, dinv, B[0], row_ptr, col,
                                       (unsigned int*)xyh, (unsigned int*)xyr, N);
  for (int l = 1; l <= 3; ++l) {
    gemm_mfma<128><<<gb64, 256, 0, stream>>>(xyh, xyr, wh + l * 16384, wr + l * 16384, dinv, g, N);
    aggregate128<<<ab, 256, 0, stream>>>((const unsigned int*)g, dinv, B[l], row_ptr, col,
                                         (unsigned int*)xyh, (unsigned int*)xyr, N);
  }
  gemm_mfma<64><<<gb64, 256, 0, stream>>>(xyh, xyr, wh + 4 * 16384, wr + 4 * 16384, dinv, g, N);
  aggregate64<<<ab, 256, 0, stream>>>((const unsigned short*)g, dinv, B[4], row_ptr, col, (float*)d_out, N);
}

// Round 12
// 293.654 us; speedup vs baseline: 2.5226x; 1.0682x over previous
//
#include <hip/hip_runtime.h>
#include <hip/hip_fp16.h>
#include <math.h>

// GCN: out = D^-1/2 (A+I) D^-1/2 (x W^T) + b per layer, ReLU between layers.
// Final config (R12) = best measured pieces:
//   - counting-sort graph build (R6): write-locality without occupancy loss
//   - MFMA split-fp16 GEMM (R3), layer-0 reads fp32 x directly (R11, exact)
//   - ILP-8 wave-per-node gather (R8) — measured fastest across ILP 4/8/16,
//     chunked-locality (R7/R10) and fusion (R9) all slower.
// Aggregate is pinned at random-gather request throughput (~5.4 TB/s logical,
// L2/L3-served); 5 layers x ~40us is the structural floor.

typedef _Float16 f16x8 __attribute__((ext_vector_type(8)));
typedef float f32x4 __attribute__((ext_vector_type(4)));

#define NBIN 128
#define NB 512       // histogram/scatter blocks
#define WCAP 12288   // k_build LDS col-window entries (48 KB)

// ---------------- graph build ----------------

__device__ __forceinline__ int edge_at(const void* ei, int is64, long long idx) {
  if (is64) return (int)((const long long*)ei)[idx];
  return ((const int*)ei)[idx];
}

__device__ __forceinline__ int detect_is64(const int* ei32, int E, int* ldsflag, int tid) {
  if (tid == 0) *ldsflag = 0;
  __syncthreads();
  int lim = (E < 256) ? E : 256;
  if (tid < lim) {
    if (ei32[2 * tid + 1] != 0) atomicOr(ldsflag, 1);
  }
  __syncthreads();
  return (*ldsflag == 0) ? 1 : 0;
}

__global__ __launch_bounds__(512) void k_cnt2(const void* __restrict__ ei, int* __restrict__ bcnt,
                                              int E, int n, int W) {
  __shared__ int cnt[NBIN];
  __shared__ int f64;
  int t = threadIdx.x;
  int is64 = detect_is64((const int*)ei, E, &f64, t);
  if (t < NBIN) cnt[t] = 0;
  __syncthreads();
  int chunk = (E + NB - 1) / NB;
  int base = blockIdx.x * chunk;
  int end = base + chunk;
  if (end > E) end = E;
  for (int i = base + t; i < end; i += 512) {
    int s = edge_at(ei, is64, i);
    int v = edge_at(ei, is64, (long long)E + i);
    if ((unsigned)v < (unsigned)n && (unsigned)s < (unsigned)n) atomicAdd(&cnt[v / W], 1);
  }
  __syncthreads();
  if (t < NBIN) bcnt[blockIdx.x * NBIN + t] = cnt[t];
}

__global__ __launch_bounds__(256) void k_scanb(int* __restrict__ bcnt, int* __restrict__ bintot) {
  __shared__ int buf[NB];
  int bin = blockIdx.x;
  int t = threadIdx.x;
  int a0 = bcnt[(size_t)t * NBIN + bin];
  int a1 = bcnt[(size_t)(t + 256) * NBIN + bin];
  buf[t] = a0;
  buf[t + 256] = a1;
  __syncthreads();
  for (int off = 1; off < NB; off <<= 1) {
    int x0 = (t >= off) ? buf[t - off] : 0;
    int x1 = (t + 256 >= off) ? buf[t + 256 - off] : 0;
    __syncthreads();
    buf[t] += x0;
    buf[t + 256] += x1;
    __syncthreads();
  }
  bcnt[(size_t)t * NBIN + bin] = buf[t] - a0;
  bcnt[(size_t)(t + 256) * NBIN + bin] = buf[t + 256] - a1;
  if (t == 255) bintot[bin] = buf[NB - 1];
}

__global__ __launch_bounds__(512) void k_scat(const void* __restrict__ ei, const int* __restrict__ bintot,
                                              const int* __restrict__ bcnt, uint2* __restrict__ ebin,
                                              int E, int n, int W) {
  __shared__ int f64;
  __shared__ int sb[NBIN];
  __shared__ int cur[NBIN];
  int t = threadIdx.x;
  int is64 = detect_is64((const int*)ei, E, &f64, t);
  if (t < NBIN) sb[t] = bintot[t];
  __syncthreads();
  for (int off = 1; off < NBIN; off <<= 1) {
    int x = 0;
    if (t < NBIN && t >= off) x = sb[t - off];
    __syncthreads();
    if (t < NBIN) sb[t] += x;
    __syncthreads();
  }
  if (t < NBIN) cur[t] = sb[t] - bintot[t] + bcnt[blockIdx.x * NBIN + t];
  __syncthreads();
  int chunk = (E + NB - 1) / NB;
  int base = blockIdx.x * chunk;
  int end = base + chunk;
  if (end > E) end = E;
  for (int i = base + t; i < end; i += 512) {
    int s = edge_at(ei, is64, i);
    int v = edge_at(ei, is64, (long long)E + i);
    if ((unsigned)v < (unsigned)n && (unsigned)s < (unsigned)n) {
      int pos = atomicAdd(&cur[v / W], 1);
      ebin[pos] = make_uint2((unsigned)s, (unsigned)v);
    }
  }
}

__global__ __launch_bounds__(256) void k_build(const uint2* __restrict__ ebin, const int* __restrict__ bintot,
                                               int* __restrict__ row_ptr, float* __restrict__ dinv,
                                               int* __restrict__ col, int n, int W) {
  __shared__ int hist[512];
  __shared__ int scanBuf[512];
  __shared__ int sb[NBIN];
  __shared__ unsigned int win[WCAP];
  int t = threadIdx.x;
  int b = blockIdx.x;
  if (t < NBIN) sb[t] = bintot[t];
  __syncthreads();
  for (int off = 1; off < NBIN; off <<= 1) {
    int x = 0;
    if (t < NBIN && t >= off) x = sb[t - off];
    __syncthreads();
    if (t < NBIN) sb[t] += x;
    __syncthreads();
  }
  int ebase = sb[b] - bintot[b];
  int ecnt = bintot[b];
  int etotal = sb[NBIN - 1];

  int v0 = b * W;
  int v1 = v0 + W;
  if (v1 > n) v1 = n;
  int nloc = v1 - v0;
  if (nloc <= 0) {
    if (b == NBIN - 1 && t == 0) row_ptr[n] = etotal;
    return;
  }

  for (int i = t; i < 512; i += 256) { hist[i] = 0; scanBuf[i] = 0; }
  __syncthreads();
  for (int j = t; j < ecnt; j += 256) {
    uint2 e = ebin[ebase + j];
    atomicAdd(&hist[(int)e.y - v0], 1);
  }
  __syncthreads();
  for (int i = t; i < nloc; i += 256) {
    scanBuf[i] = hist[i];
    dinv[v0 + i] = 1.0f / sqrtf((float)(hist[i] + 1));  // +1 self-loop
  }
  __syncthreads();
  int i1 = t, i2 = t + 256;
  for (int off = 1; off < 512; off <<= 1) {
    int a = (i1 >= off) ? scanBuf[i1 - off] : 0;
    int c = (i2 >= off) ? scanBuf[i2 - off] : 0;
    __syncthreads();
    scanBuf[i1] += a;
    scanBuf[i2] += c;
    __syncthreads();
  }
  for (int i = t; i < nloc; i += 256) row_ptr[v0 + i] = ebase + scanBuf[i] - hist[i];
  if (b == NBIN - 1 && t == 0) row_ptr[n] = etotal;
  __syncthreads();
  for (int i = t; i < nloc; i += 256) hist[i] = scanBuf[i] - hist[i];  // cursor
  __syncthreads();
  if (ecnt <= WCAP) {
    for (int j = t; j < ecnt; j += 256) {
      uint2 e = ebin[ebase + j];
      int pos = atomicAdd(&hist[(int)e.y - v0], 1);
      win[pos] = e.x;
    }
    __syncthreads();
    for (int j = t; j < ecnt; j += 256) col[ebase + j] = (int)win[j];  // coalesced
  } else {
    for (int j = t; j < ecnt; j += 256) {
      uint2 e = ebin[ebase + j];
      int pos = atomicAdd(&hist[(int)e.y - v0], 1);
      col[ebase + pos] = (int)e.x;
    }
  }
}

// ---------------- weight split ----------------

__global__ __launch_bounds__(256) void k_split_wall(const float* __restrict__ W0, const float* __restrict__ W1,
                                                    const float* __restrict__ W2, const float* __restrict__ W3,
                                                    const float* __restrict__ W4, unsigned short* __restrict__ Wh,
                                                    unsigned short* __restrict__ Wr, int total) {
  int i = blockIdx.x * 256 + threadIdx.x;
  if (i >= total) return;
  const float* src;
  int off;
  if (i < 65536) {
    int l = i >> 14;
    off = i & 16383;
    src = (l == 0) ? W0 : (l == 1) ? W1 : (l == 2) ? W2 : W3;
  } else {
    off = i - 65536;
    src = W4;
  }
  float v = src[off];
  __half h = __float2half(v);
  float r = v - __half2float(h);
  __half rh = __float2half(r);
  Wh[i] = *(unsigned short*)&h;
  Wr[i] = *(unsigned short*)&rh;
}

// ---------------- MFMA GEMMs ----------------

template <int DO>
__device__ __forceinline__ void gemm_core(const f16x8 ah[4], const f16x8 ar[4],
                                          const float* __restrict__ dinv, __half* __restrict__ G,
                                          unsigned short* sWh, unsigned short* sWr,
                                          int tid, int n, int gr0) {
  constexpr int NCG = DO / 16;
  const int l = tid & 63;
  const int m = l & 15;
  const int ks = l >> 4;

  f32x4 acc[NCG];
#pragma unroll
  for (int c = 0; c < NCG; ++c) acc[c] = {0.f, 0.f, 0.f, 0.f};

  __syncthreads();

#pragma unroll
  for (int kb = 0; kb < 4; ++kb) {
    int ch = (kb * 4 + ks) ^ (m & 7);
#pragma unroll
    for (int c = 0; c < NCG; ++c) {
      int brow = c * 16 + m;
      f16x8 bh = *(const f16x8*)&sWh[brow * 128 + ch * 8];
      f16x8 br = *(const f16x8*)&sWr[brow * 128 + ch * 8];
      acc[c] = __builtin_amdgcn_mfma_f32_16x16x32_f16(ah[kb], bh, acc[c], 0, 0, 0);
      acc[c] = __builtin_amdgcn_mfma_f32_16x16x32_f16(ah[kb], br, acc[c], 0, 0, 0);
      acc[c] = __builtin_amdgcn_mfma_f32_16x16x32_f16(ar[kb], bh, acc[c], 0, 0, 0);
    }
  }

  int r0 = gr0 + ks * 4;
  float dv[4];
#pragma unroll
  for (int i = 0; i < 4; ++i) dv[i] = (r0 + i < n) ? dinv[r0 + i] : 0.f;
#pragma unroll
  for (int c = 0; c < NCG; ++c) {
#pragma unroll
    for (int i = 0; i < 4; ++i) {
      int row = r0 + i;
      if (row < n) G[(size_t)row * DO + c * 16 + m] = __float2half(dv[i] * acc[c][i]);
    }
  }
}

template <int DO>
__device__ __forceinline__ void stage_w(const unsigned short* __restrict__ Wh,
                                        const unsigned short* __restrict__ Wr,
                                        unsigned short* sWh, unsigned short* sWr, int tid) {
#pragma unroll
  for (int it = 0; it < DO / 16; ++it) {
    int t = it * 256 + tid;
    int row = t >> 4, ch = t & 15;
    int sch = ch ^ (row & 7);
    *(uint4*)&sWh[row * 128 + sch * 8] = *(const uint4*)&Wh[(size_t)t * 8];
    *(uint4*)&sWr[row * 128 + sch * 8] = *(const uint4*)&Wr[(size_t)t * 8];
  }
}

template <int DO>
__global__ __launch_bounds__(256) void gemm_mfma(const unsigned short* __restrict__ Xh,
                                                 const unsigned short* __restrict__ Xr,
                                                 const unsigned short* __restrict__ Wh,
                                                 const unsigned short* __restrict__ Wr,
                                                 const float* __restrict__ dinv, __half* __restrict__ G, int n) {
  __shared__ unsigned short sWh[DO * 128];
  __shared__ unsigned short sWr[DO * 128];
  const int tid = threadIdx.x;
  stage_w<DO>(Wh, Wr, sWh, sWr, tid);

  const int wv = tid >> 6;
  const int l = tid & 63;
  const int m = l & 15;
  const int ks = l >> 4;
  const int gr0 = blockIdx.x * 64 + wv * 16;
  const int arow = gr0 + m;

  f16x8 ah[4], ar[4];
  const f16x8 z8 = {0, 0, 0, 0, 0, 0, 0, 0};
#pragma unroll
  for (int kb = 0; kb < 4; ++kb) {
    int koff = kb * 32 + ks * 8;
    if (arow < n) {
      ah[kb] = *(const f16x8*)&Xh[(size_t)arow * 128 + koff];
      ar[kb] = *(const f16x8*)&Xr[(size_t)arow * 128 + koff];
    } else {
      ah[kb] = z8;
      ar[kb] = z8;
    }
  }
  gemm_core<DO>(ah, ar, dinv, G, sWh, sWr, tid, n, gr0);
}

// layer 0: A read as fp32 from x, split h/r in-register (bit-identical to the
// separate split pass; deletes 38MB of traffic).
__global__ __launch_bounds__(256) void gemm_mfma_f32(const float* __restrict__ X,
                                                     const unsigned short* __restrict__ Wh,
                                                     const unsigned short* __restrict__ Wr,
                                                     const float* __restrict__ dinv, __half* __restrict__ G, int n) {
  __shared__ unsigned short sWh[128 * 128];
  __shared__ unsigned short sWr[128 * 128];
  const int tid = threadIdx.x;
  stage_w<128>(Wh, Wr, sWh, sWr, tid);

  const int wv = tid >> 6;
  const int l = tid & 63;
  const int m = l & 15;
  const int ks = l >> 4;
  const int gr0 = blockIdx.x * 64 + wv * 16;
  const int arow = gr0 + m;

  f16x8 ah[4], ar[4];
#pragma unroll
  for (int kb = 0; kb < 4; ++kb) {
    int koff = kb * 32 + ks * 8;
    if (arow < n) {
      float4 v0 = *(const float4*)&X[(size_t)arow * 128 + koff];
      float4 v1 = *(const float4*)&X[(size_t)arow * 128 + koff + 4];
      float vv[8] = {v0.x, v0.y, v0.z, v0.w, v1.x, v1.y, v1.z, v1.w};
#pragma unroll
      for (int j = 0; j < 8; ++j) {
        _Float16 h = (_Float16)vv[j];  // RNE == __float2half
        float r = vv[j] - (float)h;
        ah[kb][j] = h;
        ar[kb][j] = (_Float16)r;
      }
    } else {
#pragma unroll
      for (int j = 0; j < 8; ++j) { ah[kb][j] = (_Float16)0.f; ar[kb][j] = (_Float16)0.f; }
    }
  }
  gemm_core<128>(ah, ar, dinv, G, sWh, sWr, tid, n, gr0);
}

// ---------------- aggregation (R8 ILP-8, measured fastest) ----------------

__device__ __forceinline__ float2 h2f(unsigned int u) {
  __half2 h = *(__half2*)&u;
  return __half22float2(h);
}

__global__ __launch_bounds__(256) void aggregate128(const unsigned int* __restrict__ G, const float* __restrict__ dinv,
                                                    const float* __restrict__ bias, const int* __restrict__ rp,
                                                    const int* __restrict__ col, unsigned int* __restrict__ Yh,
                                                    unsigned int* __restrict__ Yr, int n) {
  int v = (int)((blockIdx.x * 256 + threadIdx.x) >> 6);
  int lane = threadIdx.x & 63;
  if (v >= n) return;
  int s = rp[v], e = rp[v + 1];
  float2 a0 = h2f(G[(size_t)v * 64 + lane]);  // self-loop
  float2 a1 = make_float2(0.f, 0.f), a2 = make_float2(0.f, 0.f), a3 = make_float2(0.f, 0.f);
  float2 a4 = make_float2(0.f, 0.f), a5 = make_float2(0.f, 0.f);
  float2 a6 = make_float2(0.f, 0.f), a7 = make_float2(0.f, 0.f);
  int t = s;
  while (t < e) {
    int batch = e - t;
    if (batch > 64) batch = 64;
    int ci = col[t + (lane < batch ? lane : batch - 1)];
    int j = 0;
    for (; j + 8 <= batch; j += 8) {
      int u0 = __shfl(ci, j, 64), u1 = __shfl(ci, j + 1, 64);
      int u2 = __shfl(ci, j + 2, 64), u3 = __shfl(ci, j + 3, 64);
      int u4 = __shfl(ci, j + 4, 64), u5 = __shfl(ci, j + 5, 64);
      int u6 = __shfl(ci, j + 6, 64), u7 = __shfl(ci, j + 7, 64);
      unsigned int g0 = G[(size_t)u0 * 64 + lane];
      unsigned int g1 = G[(size_t)u1 * 64 + lane];
      unsigned int g2 = G[(size_t)u2 * 64 + lane];
      unsigned int g3 = G[(size_t)u3 * 64 + lane];
      unsigned int g4 = G[(size_t)u4 * 64 + lane];
      unsigned int g5 = G[(size_t)u5 * 64 + lane];
      unsigned int g6 = G[(size_t)u6 * 64 + lane];
      unsigned int g7 = G[(size_t)u7 * 64 + lane];
      float2 f0 = h2f(g0), f1 = h2f(g1), f2 = h2f(g2), f3 = h2f(g3);
      float2 f4 = h2f(g4), f5 = h2f(g5), f6 = h2f(g6), f7 = h2f(g7);
      a0.x += f0.x; a0.y += f0.y;
      a1.x += f1.x; a1.y += f1.y;
      a2.x += f2.x; a2.y += f2.y;
      a3.x += f3.x; a3.y += f3.y;
      a4.x += f4.x; a4.y += f4.y;
      a5.x += f5.x; a5.y += f5.y;
      a6.x += f6.x; a6.y += f6.y;
      a7.x += f7.x; a7.y += f7.y;
    }
    for (; j < batch; ++j) {
      int u = __shfl(ci, j, 64);
      float2 f = h2f(G[(size_t)u * 64 + lane]);
      a0.x += f.x; a0.y += f.y;
    }
    t += batch;
  }
  float sx = ((a0.x + a1.x) + (a2.x + a3.x)) + ((a4.x + a5.x) + (a6.x + a7.x));
  float sy = ((a0.y + a1.y) + (a2.y + a3.y)) + ((a4.y + a5.y) + (a6.y + a7.y));
  float dv = dinv[v];
  float2 bb = ((const float2*)bias)[lane];
  float ox = fmaxf(fmaf(dv, sx, bb.x), 0.f);  // ReLU
  float oy = fmaxf(fmaf(dv, sy, bb.y), 0.f);
  __half hx = __float2half(ox), hy = __float2half(oy);
  float rx = ox - __half2float(hx), ry = oy - __half2float(hy);
  __half rxh = __float2half(rx), ryh = __float2half(ry);
  size_t o = (size_t)v * 64 + lane;
  Yh[o] = ((unsigned int)*(unsigned short*)&hy << 16) | *(unsigned short*)&hx;
  Yr[o] = ((unsigned int)*(unsigned short*)&ryh << 16) | *(unsigned short*)&rxh;
}

__global__ __launch_bounds__(256) void aggregate64(const unsigned short* __restrict__ G, const float* __restrict__ dinv,
                                                   const float* __restrict__ bias, const int* __restrict__ rp,
                                                   const int* __restrict__ col, float* __restrict__ Y, int n) {
  int v = (int)((blockIdx.x * 256 + threadIdx.x) >> 6);
  int lane = threadIdx.x & 63;
  if (v >= n) return;
  int s = rp[v], e = rp[v + 1];
  float a0 = __half2float(*(const __half*)&G[(size_t)v * 64 + lane]);
  float a1 = 0.f, a2 = 0.f, a3 = 0.f;
  float a4 = 0.f, a5 = 0.f, a6 = 0.f, a7 = 0.f;
  int t = s;
  while (t < e) {
    int batch = e - t;
    if (batch > 64) batch = 64;
    int ci = col[t + (lane < batch ? lane : batch - 1)];
    int j = 0;
    for (; j + 8 <= batch; j += 8) {
      int u0 = __shfl(ci, j, 64), u1 = __shfl(ci, j + 1, 64);
      int u2 = __shfl(ci, j + 2, 64), u3 = __shfl(ci, j + 3, 64);
      int u4 = __shfl(ci, j + 4, 64), u5 = __shfl(ci, j + 5, 64);
      int u6 = __shfl(ci, j + 6, 64), u7 = __shfl(ci, j + 7, 64);
      unsigned short g0 = G[(size_t)u0 * 64 + lane];
      unsigned short g1 = G[(size_t)u1 * 64 + lane];
      unsigned short g2 = G[(size_t)u2 * 64 + lane];
      unsigned short g3 = G[(size_t)u3 * 64 + lane];
      unsigned short g4 = G[(size_t)u4 * 64 + lane];
      unsigned short g5 = G[(size_t)u5 * 64 + lane];
      unsigned short g6 = G[(size_t)u6 * 64 + lane];
      unsigned short g7 = G[(size_t)u7 * 64 + lane];
      a0 += __half2float(*(const __half*)&g0);
      a1 += __half2float(*(const __half*)&g1);
      a2 += __half2float(*(const __half*)&g2);
      a3 += __half2float(*(const __half*)&g3);
      a4 += __half2float(*(const __half*)&g4);
      a5 += __half2float(*(const __half*)&g5);
      a6 += __half2float(*(const __half*)&g6);
      a7 += __half2float(*(const __half*)&g7);
    }
    for (; j < batch; ++j) {
      int u = __shfl(ci, j, 64);
      unsigned short g = G[(size_t)u * 64 + lane];
      a0 += __half2float(*(const __half*)&g);
    }
    t += batch;
  }
  float sum = ((a0 + a1) + (a2 + a3)) + ((a4 + a5) + (a6 + a7));
  Y[(size_t)v * 64 + lane] = fmaf(dinv[v], sum, bias[lane]);
}

// ---------------- launch ----------------

extern "C" void kernel_launch(void* const* d_in, const int* in_sizes, int n_in,
                              void* d_out, int out_size, void* d_ws, size_t ws_size,
                              hipStream_t stream) {
  const float* x = (const float*)d_in[0];
  const void* ei = d_in[1];
  const int N = in_sizes[0] / 128;
  const int E = in_sizes[1] / 2;
  const float* W[5] = {(const float*)d_in[2], (const float*)d_in[4], (const float*)d_in[6],
                       (const float*)d_in[8], (const float*)d_in[10]};
  const float* B[5] = {(const float*)d_in[3], (const float*)d_in[5], (const float*)d_in[7],
                       (const float*)d_in[9], (const float*)d_in[11]};
  const int Wbin = (N + NBIN - 1) / NBIN;

  char* p = (char*)d_ws;
  unsigned short* xyh = (unsigned short*)p;  p += (size_t)N * 128 * 2;   // activations h
  unsigned short* xyr = (unsigned short*)p;  p += (size_t)N * 128 * 2;   // activations r
  __half* g = (__half*)p;                    p += (size_t)N * 128 * 2;   // post-GEMM dinv.*h
  uint2* ebin = (uint2*)g;                   // ALIAS: ebin dead before gemm0 writes g
  unsigned short* wh = (unsigned short*)p;   p += (size_t)5 * 16384 * 2;
  unsigned short* wr = (unsigned short*)p;   p += (size_t)5 * 16384 * 2;
  float* dinv = (float*)p;                   p += (size_t)N * 4;
  int* col = (int*)p;                        p += (size_t)E * 4;
  int* row_ptr = (int*)p;                    p += (size_t)(N + 1) * 4;
  int* bcnt = (int*)p;                       p += (size_t)NB * NBIN * 4;
  int* bintot = (int*)p;                     p += NBIN * 4;

  k_cnt2<<<NB, 512, 0, stream>>>(ei, bcnt, E, N, Wbin);
  k_scanb<<<NBIN, 256, 0, stream>>>(bcnt, bintot);
  k_scat<<<NB, 512, 0, stream>>>(ei, bintot, bcnt, ebin, E, N, Wbin);
  k_build<<<NBIN, 256, 0, stream>>>(ebin, bintot, row_ptr, dinv, col, N, Wbin);

  k_split_wall<<<(73728 + 255) / 256, 256, 0, stream>>>(W[0], W[1], W[2], W[3], W[4], wh, wr, 73728);

  const int gb64 = (N + 63) / 64;
  const int ab = (N * 64 + 255) / 256;

  // layer 0: fp32 x read directly (in-register split) -> g
  gemm_mfma_f32<<<gb64, 256, 0, stream>>>(x, wh, wr, dinv, g, N);
  aggregate128<<<ab, 256, 0, stream>>>((const unsigned int*)g, dinv, B[0], row_ptr, col,
                                       (unsigned int*)xyh, (unsigned int*)xyr, N);
  for (int l = 1; l <= 3; ++l) {
    gemm_mfma<128><<<gb64, 256, 0, stream>>>(xyh, xyr, wh + l * 16384, wr + l * 16384, dinv, g, N);
    aggregate128<<<ab, 256, 0, stream>>>((const unsigned int*)g, dinv, B[l], row_ptr, col,
                                         (unsigned int*)xyh, (unsigned int*)xyr, N);
  }
  gemm_mfma<64><<<gb64, 256, 0, stream>>>(xyh, xyr, wh + 4 * 16384, wr + 4 * 16384, dinv, g, N);
  aggregate64<<<ab, 256, 0, stream>>>((const unsigned short*)g, dinv, B[4], row_ptr, col, (float*)d_out, N);
}